// Round 11
// baseline (45.448 us; speedup 1.0000x reference)
//
#include <hip/hip_runtime.h>
#include <hip/hip_fp16.h>
#include <math.h>

// PerVertQuaternion, round 11: byte-residue sort + global counts + fused tail.
//
// Pipeline (structured faces, i.e. (i0,i0+1,i0+2) mod V -> w depends only
// on i0, so only count[i0] matters):
//   zero(E)  -> sort: block-major counting sort writing RESIDUE BYTES
//               (i0&255) into block-owned S1 chunks; run descriptors Hoff.
//               Unstructured faces -> f32 atomics on E (rare/none).
//   count    -> per bucket: walk 256 runs, count residues in LDS,
//               coalesced uint write of count[v]  (2 MB).
//   finish   -> per 256-row block: compute w for rows [base-2, base+256)
//               (258 evals, coalesced vertex reads), Tl[j]=count*w in LDS,
//               out[v] = nrm(Tl[t+2]+Tl[t+1]+Tl[t]+E[v]).  No T buffer.
//
// Session laws: scattered global WRITES catastrophic (~19G sectors/s,
// cross-XCD write-through); scattered READS cheap; rocclr memset slow;
// keep scatters block-owned (XCD-local).

#define BS      256     // bases per bucket
#define NBMAX   2048    // max buckets (V <= 524288)
#define NBLK1   256     // sort blocks (== count kernel blockDim)
#define CHMAX   4096    // max faces per sort block (F <= 1,048,576)

struct V3 { float x, y, z; };

__device__ __forceinline__ V3 v3sub(const V3& a, const V3& b) {
    return V3{a.x - b.x, a.y - b.y, a.z - b.z};
}
__device__ __forceinline__ V3 v3cross(const V3& a, const V3& b) {
    return V3{a.y * b.z - a.z * b.y,
              a.z * b.x - a.x * b.z,
              a.x * b.y - a.y * b.x};
}
__device__ __forceinline__ float v3dot(const V3& a, const V3& b) {
    return a.x * b.x + a.y * b.y + a.z * b.z;
}
__device__ __forceinline__ V3 v3nrm(const V3& v) {
    float n = sqrtf(v3dot(v, v));
    float inv = 1.0f / fmaxf(n, 1e-12f);
    return V3{v.x * inv, v.y * inv, v.z * inv};
}
__device__ __forceinline__ V3 loadv(const float* __restrict__ p, int i) {
    return V3{p[3 * i], p[3 * i + 1], p[3 * i + 2]};
}

__device__ __forceinline__ void tri2frame(const V3& a, const V3& b, const V3& c,
                                          V3& X, V3& Y, V3& Z) {
    V3 n = v3nrm(v3cross(v3sub(b, a), v3sub(c, a)));
    V3 d = v3sub(b, a);
    X = v3nrm(v3cross(d, n));
    Y = v3nrm(v3cross(d, X));
    Z = v3nrm(d);
}

__device__ __forceinline__ void face_core(V3 ca, V3 cb, V3 cc,
                                          V3 da, V3 db, V3 dc,
                                          float& w0, float& w1, float& w2, float& w3) {
    V3 fn = v3cross(v3sub(cc, cb), v3sub(ca, cb));
    float area = 0.5f * sqrtf(v3dot(fn, fn));

    V3 Xc, Yc, Zc, Xd, Yd, Zd;
    tri2frame(ca, cb, cc, Xc, Yc, Zc);
    tri2frame(da, db, dc, Xd, Yd, Zd);

    // Rot = R_deform * R_cano^T (orthonormal frames -> inv == transpose)
    float Rd[3][3] = {{Xd.x, Yd.x, Zd.x}, {Xd.y, Yd.y, Zd.y}, {Xd.z, Yd.z, Zd.z}};
    float Rc[3][3] = {{Xc.x, Yc.x, Zc.x}, {Xc.y, Yc.y, Zc.y}, {Xc.z, Yc.z, Zc.z}};
    float m00 = Rd[0][0]*Rc[0][0] + Rd[0][1]*Rc[0][1] + Rd[0][2]*Rc[0][2];
    float m01 = Rd[0][0]*Rc[1][0] + Rd[0][1]*Rc[1][1] + Rd[0][2]*Rc[1][2];
    float m02 = Rd[0][0]*Rc[2][0] + Rd[0][1]*Rc[2][1] + Rd[0][2]*Rc[2][2];
    float m10 = Rd[1][0]*Rc[0][0] + Rd[1][1]*Rc[0][1] + Rd[1][2]*Rc[0][2];
    float m11 = Rd[1][0]*Rc[1][0] + Rd[1][1]*Rc[1][1] + Rd[1][2]*Rc[1][2];
    float m12 = Rd[1][0]*Rc[2][0] + Rd[1][1]*Rc[2][1] + Rd[1][2]*Rc[2][2];
    float m20 = Rd[2][0]*Rc[0][0] + Rd[2][1]*Rc[0][1] + Rd[2][2]*Rc[0][2];
    float m21 = Rd[2][0]*Rc[1][0] + Rd[2][1]*Rc[1][1] + Rd[2][2]*Rc[1][2];
    float m22 = Rd[2][0]*Rc[2][0] + Rd[2][1]*Rc[2][1] + Rd[2][2]*Rc[2][2];

    float t0 = 1.0f + m00 + m11 + m22;
    float t1 = 1.0f + m00 - m11 - m22;
    float t2 = 1.0f - m00 + m11 - m22;
    float t3 = 1.0f - m00 - m11 + m22;
    float qa0 = t0 > 0.0f ? sqrtf(t0) : 0.0f;
    float qa1 = t1 > 0.0f ? sqrtf(t1) : 0.0f;
    float qa2 = t2 > 0.0f ? sqrtf(t2) : 0.0f;
    float qa3 = t3 > 0.0f ? sqrtf(t3) : 0.0f;

    int best = 0; float qb = qa0;
    if (qa1 > qb) { best = 1; qb = qa1; }
    if (qa2 > qb) { best = 2; qb = qa2; }
    if (qa3 > qb) { best = 3; qb = qa3; }

    float q0, q1, q2, q3;
    if (best == 0)      { q0 = qa0*qa0; q1 = m21-m12; q2 = m02-m20; q3 = m10-m01; }
    else if (best == 1) { q0 = m21-m12; q1 = qa1*qa1; q2 = m10+m01; q3 = m02+m20; }
    else if (best == 2) { q0 = m02-m20; q1 = m10+m01; q2 = qa2*qa2; q3 = m12+m21; }
    else                { q0 = m10-m01; q1 = m20+m02; q2 = m21+m12; q3 = qa3*qa3; }
    float scale = area / (2.0f * fmaxf(qb, 0.1f));
    w0 = q0 * scale; w1 = q1 * scale; w2 = q2 * scale; w3 = q3 * scale;
}

__device__ __forceinline__ void face_math(const float* __restrict__ mesh,
                                          const float* __restrict__ cano,
                                          int i0, int i1, int i2,
                                          float& w0, float& w1, float& w2, float& w3) {
    face_core(loadv(cano, i0), loadv(cano, i1), loadv(cano, i2),
              loadv(mesh, i0), loadv(mesh, i1), loadv(mesh, i2),
              w0, w1, w2, w3);
}

__device__ __forceinline__ bool is_structured(int i0, int i1, int i2, int V) {
    int e1 = (i0 + 1 < V) ? i0 + 1 : i0 + 1 - V;
    int e2 = (i0 + 2 < V) ? i0 + 2 : i0 + 2 - V;
    return (i1 == e1) & (i2 == e2);
}

// ---------------- P0: zero E ------------------------------------------------
__global__ __launch_bounds__(256)
void zero_kernel(float4* __restrict__ E4, int nE4) {
    int stride = gridDim.x * 256;
    for (int i = blockIdx.x * 256 + threadIdx.x; i < nE4; i += stride)
        E4[i] = make_float4(0.f, 0.f, 0.f, 0.f);
}

// ---------------- P1: counting sort -> residue bytes in block-major S1 ------
__global__ __launch_bounds__(1024)
void sort_kernel(const float* __restrict__ mesh,
                 const float* __restrict__ cano,
                 const int* __restrict__ faces,
                 unsigned int* __restrict__ Hoff,      // [NBLK1][NB] off|cnt<<16
                 unsigned char* __restrict__ S1,       // [NBLK1][CHUNKF] residue bytes
                 float* __restrict__ E,
                 int F, int V, int NB, int CHUNKF) {
    __shared__ int h[NBMAX];
    __shared__ int off[NBMAX];
    __shared__ int cnt2[NBMAX];
    __shared__ int S0[CHMAX];
    __shared__ int wsum[16];

    int tid = threadIdx.x;
    for (int b = tid; b < NB; b += 1024) { h[b] = 0; cnt2[b] = 0; }
    __syncthreads();

    int beg = blockIdx.x * CHUNKF;
    int end = min(F, beg + CHUNKF);

    // pass A: histogram + cache i0 in LDS; unstructured -> E atomics inline
    for (int f = beg + tid; f < end; f += 1024) {
        int i0 = faces[3 * f + 0];
        int i1 = faces[3 * f + 1];
        int i2 = faces[3 * f + 2];
        if (is_structured(i0, i1, i2, V)) {
            S0[f - beg] = i0;
            atomicAdd(&h[i0 >> 8], 1);
        } else {
            S0[f - beg] = -1;
            float w0, w1, w2, w3;
            face_math(mesh, cano, i0, i1, i2, w0, w1, w2, w3);
            atomicAdd(&E[4*i0+0], w0); atomicAdd(&E[4*i0+1], w1);
            atomicAdd(&E[4*i0+2], w2); atomicAdd(&E[4*i0+3], w3);
            atomicAdd(&E[4*i1+0], w0); atomicAdd(&E[4*i1+1], w1);
            atomicAdd(&E[4*i1+2], w2); atomicAdd(&E[4*i1+3], w3);
            atomicAdd(&E[4*i2+0], w0); atomicAdd(&E[4*i2+1], w1);
            atomicAdd(&E[4*i2+2], w2); atomicAdd(&E[4*i2+3], w3);
        }
    }
    __syncthreads();

    // exclusive prefix over h[0..NB) -> off[]
    {
        int e0 = (2 * tid < NB)     ? h[2 * tid]     : 0;
        int e1 = (2 * tid + 1 < NB) ? h[2 * tid + 1] : 0;
        int mysum = e0 + e1;
        int lane = tid & 63, wid = tid >> 6;
        int inc = mysum;
        #pragma unroll
        for (int d = 1; d < 64; d <<= 1) {
            int up = __shfl_up(inc, d);
            if (lane >= d) inc += up;
        }
        if (lane == 63) wsum[wid] = inc;
        __syncthreads();
        if (tid == 0) {
            int run = 0;
            #pragma unroll
            for (int i = 0; i < 16; ++i) { int x = wsum[i]; wsum[i] = run; run += x; }
        }
        __syncthreads();
        int excl = wsum[wid] + inc - mysum;
        if (2 * tid < NBMAX)     off[2 * tid]     = excl;
        if (2 * tid + 1 < NBMAX) off[2 * tid + 1] = excl + e0;
    }
    __syncthreads();

    // publish packed run descriptors (coalesced)
    for (int b = tid; b < NB; b += 1024)
        Hoff[(size_t)blockIdx.x * NB + b] = (unsigned int)off[b] | ((unsigned int)h[b] << 16);

    // pass B: write residue bytes into block-owned chunk (XCD-local scatter)
    unsigned char* S1blk = S1 + (size_t)blockIdx.x * CHUNKF;
    for (int j = tid; j < end - beg; j += 1024) {
        int i0 = S0[j];
        if (i0 >= 0) {
            int b = i0 >> 8;
            int p = atomicAdd(&cnt2[b], 1);
            S1blk[off[b] + p] = (unsigned char)(i0 & 0xFF);
        }
    }
}

// ---------------- P2: per-bucket residue counting -> global count[v] --------
__global__ __launch_bounds__(256)
void count_kernel(const unsigned int* __restrict__ Hoff,
                  const unsigned char* __restrict__ S1,
                  unsigned int* __restrict__ cntA,
                  int V, int NB, int CHUNKF) {
    int b = blockIdx.x;
    if (b >= NB) return;
    __shared__ unsigned int cnt_l[BS];
    cnt_l[threadIdx.x] = 0;
    __syncthreads();

    // one run per thread (NBLK1 == blockDim == 256); tiny divergent body
    {
        int r = threadIdx.x;
        unsigned int pc = Hoff[(size_t)r * NB + b];
        int start = (int)(pc & 0xFFFFu);
        int cnt   = (int)(pc >> 16);
        const unsigned char* run = S1 + (size_t)r * CHUNKF + start;
        for (int j = 0; j < cnt; ++j)
            atomicAdd(&cnt_l[run[j]], 1u);
    }
    __syncthreads();
    int row = b * BS + (int)threadIdx.x;
    if (row < V) cntA[row] = cnt_l[threadIdx.x];
}

// ---------------- P3: fused math + shifted-sum + normalize ------------------
__global__ __launch_bounds__(256)
void finish_kernel(const float* __restrict__ mesh,
                   const float* __restrict__ cano,
                   const unsigned int* __restrict__ cntA,
                   const float* __restrict__ E,
                   float* __restrict__ out, int V) {
    __shared__ float4 Tw[BS + 2];   // Tw[j] = count*w for row base-2+j
    int base = blockIdx.x * BS;
    int t = threadIdx.x;

    for (int j = t; j < BS + 2; j += 256) {
        int row = base - 2 + j;
        if (row < 0) row += V;
        if (row >= V) row -= V;
        unsigned int c = cntA[row];
        float4 res = make_float4(0.f, 0.f, 0.f, 0.f);
        if (c > 0) {
            int i1 = (row + 1 < V) ? row + 1 : row + 1 - V;
            int i2 = (row + 2 < V) ? row + 2 : row + 2 - V;
            float w0, w1, w2, w3;
            face_math(mesh, cano, row, i1, i2, w0, w1, w2, w3);
            float fc = (float)c;
            res = make_float4(w0 * fc, w1 * fc, w2 * fc, w3 * fc);
        }
        Tw[j] = res;
    }
    __syncthreads();

    int v = base + t;
    if (v < V) {
        float4 a = Tw[t + 2], b = Tw[t + 1], c = Tw[t];
        float4 e = reinterpret_cast<const float4*>(E)[v];
        float x = a.x + b.x + c.x + e.x;
        float y = a.y + b.y + c.y + e.y;
        float z = a.z + b.z + c.z + e.z;
        float w = a.w + b.w + c.w + e.w;
        float n = sqrtf(x * x + y * y + z * z + w * w);
        float inv = 1.0f / fmaxf(n, 1e-6f);
        reinterpret_cast<float4*>(out)[v] = make_float4(x * inv, y * inv, z * inv, w * inv);
    }
}

// ================= fallback paths ===========================================
typedef _Float16 hf2 __attribute__((ext_vector_type(2)));

__device__ __forceinline__ void atomic_pk_add_f16(__half* base, float a, float b) {
#if __has_builtin(__builtin_amdgcn_global_atomic_fadd_v2f16)
    hf2 v; v.x = (_Float16)a; v.y = (_Float16)b;
    __builtin_amdgcn_global_atomic_fadd_v2f16(
        (__attribute__((address_space(1))) hf2*)base, v);
#else
    union { _Float16 h[2]; unsigned int u; } pk;
    pk.h[0] = (_Float16)a; pk.h[1] = (_Float16)b;
    asm volatile("global_atomic_pk_add_f16 %0, %1, off"
                 :: "v"(base), "v"(pk.u) : "memory");
#endif
}

__global__ void face_kernel_f16(const float* __restrict__ mesh,
                                const float* __restrict__ cano,
                                const int* __restrict__ faces,
                                __half* __restrict__ T, float* __restrict__ E,
                                int F, int V) {
    int f = blockIdx.x * blockDim.x + threadIdx.x;
    if (f >= F) return;
    int i0 = faces[3*f+0], i1 = faces[3*f+1], i2 = faces[3*f+2];
    float w0, w1, w2, w3;
    face_math(mesh, cano, i0, i1, i2, w0, w1, w2, w3);
    if (is_structured(i0, i1, i2, V)) {
        __half* t = T + 4 * (size_t)i0;
        atomic_pk_add_f16(t,     w0, w1);
        atomic_pk_add_f16(t + 2, w2, w3);
    } else {
        atomicAdd(&E[4*i0+0], w0); atomicAdd(&E[4*i0+1], w1);
        atomicAdd(&E[4*i0+2], w2); atomicAdd(&E[4*i0+3], w3);
        atomicAdd(&E[4*i1+0], w0); atomicAdd(&E[4*i1+1], w1);
        atomicAdd(&E[4*i1+2], w2); atomicAdd(&E[4*i1+3], w3);
        atomicAdd(&E[4*i2+0], w0); atomicAdd(&E[4*i2+1], w1);
        atomicAdd(&E[4*i2+2], w2); atomicAdd(&E[4*i2+3], w3);
    }
}

__global__ void finish_kernel_f16(const __half* __restrict__ T,
                                  const float* __restrict__ E,
                                  float* __restrict__ out, int V) {
    int v = blockIdx.x * blockDim.x + threadIdx.x;
    if (v >= V) return;
    int vm1 = (v >= 1) ? v - 1 : v - 1 + V;
    int vm2 = (v >= 2) ? v - 2 : v - 2 + V;
    const __half2* p0 = reinterpret_cast<const __half2*>(T + 4 * (size_t)v);
    const __half2* p1 = reinterpret_cast<const __half2*>(T + 4 * (size_t)vm1);
    const __half2* p2 = reinterpret_cast<const __half2*>(T + 4 * (size_t)vm2);
    float2 a01 = __half22float2(p0[0]), a23 = __half22float2(p0[1]);
    float2 b01 = __half22float2(p1[0]), b23 = __half22float2(p1[1]);
    float2 c01 = __half22float2(p2[0]), c23 = __half22float2(p2[1]);
    float4 e = reinterpret_cast<const float4*>(E)[v];
    float x = a01.x + b01.x + c01.x + e.x;
    float y = a01.y + b01.y + c01.y + e.y;
    float z = a23.x + b23.x + c23.x + e.z;
    float w = a23.y + b23.y + c23.y + e.w;
    float n = sqrtf(x * x + y * y + z * z + w * w);
    float inv = 1.0f / fmaxf(n, 1e-6f);
    reinterpret_cast<float4*>(out)[v] = make_float4(x * inv, y * inv, z * inv, w * inv);
}

__global__ void face_kernel_direct(const float* __restrict__ mesh,
                                   const float* __restrict__ cano,
                                   const int* __restrict__ faces,
                                   float* __restrict__ out, int F) {
    int f = blockIdx.x * blockDim.x + threadIdx.x;
    if (f >= F) return;
    int i0 = faces[3*f+0], i1 = faces[3*f+1], i2 = faces[3*f+2];
    float w0, w1, w2, w3;
    face_math(mesh, cano, i0, i1, i2, w0, w1, w2, w3);
    atomicAdd(&out[4*i0+0], w0); atomicAdd(&out[4*i0+1], w1);
    atomicAdd(&out[4*i0+2], w2); atomicAdd(&out[4*i0+3], w3);
    atomicAdd(&out[4*i1+0], w0); atomicAdd(&out[4*i1+1], w1);
    atomicAdd(&out[4*i1+2], w2); atomicAdd(&out[4*i1+3], w3);
    atomicAdd(&out[4*i2+0], w0); atomicAdd(&out[4*i2+1], w1);
    atomicAdd(&out[4*i2+2], w2); atomicAdd(&out[4*i2+3], w3);
}

__global__ void norm_kernel(float* __restrict__ out, int V) {
    int v = blockIdx.x * blockDim.x + threadIdx.x;
    if (v >= V) return;
    float4 q = reinterpret_cast<float4*>(out)[v];
    float n = sqrtf(q.x*q.x + q.y*q.y + q.z*q.z + q.w*q.w);
    float inv = 1.0f / fmaxf(n, 1e-6f);
    reinterpret_cast<float4*>(out)[v] = make_float4(q.x*inv, q.y*inv, q.z*inv, q.w*inv);
}

extern "C" void kernel_launch(void* const* d_in, const int* in_sizes, int n_in,
                              void* d_out, int out_size, void* d_ws, size_t ws_size,
                              hipStream_t stream) {
    const float* mesh  = (const float*)d_in[0];
    const float* cano  = (const float*)d_in[1];
    const int*   faces = (const int*)d_in[2];
    float* out = (float*)d_out;

    int V = in_sizes[0] / 3;
    int F = in_sizes[2] / 3;
    const int TB = 256;
    int NB = (V + BS - 1) / BS;
    int CHUNKF = (F + NBLK1 - 1) / NBLK1;

    // ws layout (byte offsets)
    size_t bHoff = (size_t)NBLK1 * NBMAX * 4;                 // 2 MB
    size_t bS1   = (((size_t)NBLK1 * CHUNKF) + 15) & ~15ull;  // ~1 MB (residue bytes)
    size_t bCnt  = (size_t)V * 4;                             // 2 MB
    size_t bE    = (size_t)V * 16;                            // 8 MB
    size_t needFull = bHoff + bS1 + bCnt + bE;

    size_t bytesTf16 = (size_t)V * 4 * sizeof(__half);
    size_t bytesEf32 = (size_t)V * 4 * sizeof(float);

    if (ws_size >= needFull && NB <= NBMAX && CHUNKF <= CHMAX) {
        unsigned int*  Hoff = (unsigned int*)d_ws;
        unsigned char* S1   = (unsigned char*)d_ws + bHoff;
        unsigned int*  cntA = (unsigned int*)((char*)d_ws + bHoff + bS1);
        float*         E    = (float*)((char*)d_ws + bHoff + bS1 + bCnt);

        zero_kernel<<<1024, 256, 0, stream>>>((float4*)E, V);
        sort_kernel<<<NBLK1, 1024, 0, stream>>>(mesh, cano, faces, Hoff, S1,
                                                E, F, V, NB, CHUNKF);
        count_kernel<<<NB, 256, 0, stream>>>(Hoff, S1, cntA, V, NB, CHUNKF);
        finish_kernel<<<NB, 256, 0, stream>>>(mesh, cano, cntA, E, out, V);
    } else if (ws_size >= bytesTf16 + bytesEf32) {
        __half* T = (__half*)d_ws;
        float*  E = (float*)((char*)d_ws + bytesTf16);
        (void)hipMemsetAsync(d_ws, 0, bytesTf16 + bytesEf32, stream);
        face_kernel_f16<<<(F + TB - 1) / TB, TB, 0, stream>>>(mesh, cano, faces, T, E, F, V);
        finish_kernel_f16<<<(V + TB - 1) / TB, TB, 0, stream>>>(T, E, out, V);
    } else {
        (void)hipMemsetAsync(out, 0, (size_t)V * 4 * sizeof(float), stream);
        face_kernel_direct<<<(F + TB - 1) / TB, TB, 0, stream>>>(mesh, cano, faces, out, F);
        norm_kernel<<<(V + TB - 1) / TB, TB, 0, stream>>>(out, V);
    }
}

// Round 12
// 41.039 us; speedup vs baseline: 1.1074x; 1.1074x over previous
//
#include <hip/hip_runtime.h>
#include <hip/hip_fp16.h>
#include <math.h>

// PerVertQuaternion, round 12: full-occupancy sort + transposed descriptors
// + E/zero elimination.
//
// R11 lesson: removing 16MB of traffic changed NOTHING -> remaining time is
// structure, not bytes: sort at 50% occupancy (~16us), count's scattered
// Hoff-column reads (~31MB effective), zero+E path (~5us) for a case that
// never occurs (all faces structured).
//
// This round:
//  sort (512 blk x 1024 thr, 2 blk/CU = full occupancy): histogram +
//    prefix + residue-byte scatter into block-owned S1 chunks. Unstructured
//    faces -> per-chunk index list (plain writes, no atomics, no init).
//  transpose: tiled coalesced Hoff[512][NB] -> HoffT[NB][512].
//  count: per bucket, contiguous 2KB descriptor row + run walk -> cntA.
//  finish: per 256-row block: w for rows base-2..base+255 (coalesced),
//    out[v] = nrm(c*w window sum [+ unstructured fixup iff any]).
//
// Session laws: scattered global WRITES catastrophic; scattered READS cheap
// but line-amplified (fixed here via transpose); traffic is NOT the limit
// below ~50us -- structure and occupancy are.

#define BS      256     // bases per bucket
#define NBMAX   2048    // max buckets (V <= 524288)
#define NBLK1   512     // sort chunks
#define CHMAX   2048    // max faces per chunk (F <= 1,048,576)

struct V3 { float x, y, z; };

__device__ __forceinline__ V3 v3sub(const V3& a, const V3& b) {
    return V3{a.x - b.x, a.y - b.y, a.z - b.z};
}
__device__ __forceinline__ V3 v3cross(const V3& a, const V3& b) {
    return V3{a.y * b.z - a.z * b.y,
              a.z * b.x - a.x * b.z,
              a.x * b.y - a.y * b.x};
}
__device__ __forceinline__ float v3dot(const V3& a, const V3& b) {
    return a.x * b.x + a.y * b.y + a.z * b.z;
}
__device__ __forceinline__ V3 v3nrm(const V3& v) {
    float n = sqrtf(v3dot(v, v));
    float inv = 1.0f / fmaxf(n, 1e-12f);
    return V3{v.x * inv, v.y * inv, v.z * inv};
}
__device__ __forceinline__ V3 loadv(const float* __restrict__ p, int i) {
    return V3{p[3 * i], p[3 * i + 1], p[3 * i + 2]};
}

__device__ __forceinline__ void tri2frame(const V3& a, const V3& b, const V3& c,
                                          V3& X, V3& Y, V3& Z) {
    V3 n = v3nrm(v3cross(v3sub(b, a), v3sub(c, a)));
    V3 d = v3sub(b, a);
    X = v3nrm(v3cross(d, n));
    Y = v3nrm(v3cross(d, X));
    Z = v3nrm(d);
}

__device__ __forceinline__ void face_core(V3 ca, V3 cb, V3 cc,
                                          V3 da, V3 db, V3 dc,
                                          float& w0, float& w1, float& w2, float& w3) {
    V3 fn = v3cross(v3sub(cc, cb), v3sub(ca, cb));
    float area = 0.5f * sqrtf(v3dot(fn, fn));

    V3 Xc, Yc, Zc, Xd, Yd, Zd;
    tri2frame(ca, cb, cc, Xc, Yc, Zc);
    tri2frame(da, db, dc, Xd, Yd, Zd);

    // Rot = R_deform * R_cano^T (orthonormal frames -> inv == transpose)
    float Rd[3][3] = {{Xd.x, Yd.x, Zd.x}, {Xd.y, Yd.y, Zd.y}, {Xd.z, Yd.z, Zd.z}};
    float Rc[3][3] = {{Xc.x, Yc.x, Zc.x}, {Xc.y, Yc.y, Zc.y}, {Xc.z, Yc.z, Zc.z}};
    float m00 = Rd[0][0]*Rc[0][0] + Rd[0][1]*Rc[0][1] + Rd[0][2]*Rc[0][2];
    float m01 = Rd[0][0]*Rc[1][0] + Rd[0][1]*Rc[1][1] + Rd[0][2]*Rc[1][2];
    float m02 = Rd[0][0]*Rc[2][0] + Rd[0][1]*Rc[2][1] + Rd[0][2]*Rc[2][2];
    float m10 = Rd[1][0]*Rc[0][0] + Rd[1][1]*Rc[0][1] + Rd[1][2]*Rc[0][2];
    float m11 = Rd[1][0]*Rc[1][0] + Rd[1][1]*Rc[1][1] + Rd[1][2]*Rc[1][2];
    float m12 = Rd[1][0]*Rc[2][0] + Rd[1][1]*Rc[2][1] + Rd[1][2]*Rc[2][2];
    float m20 = Rd[2][0]*Rc[0][0] + Rd[2][1]*Rc[0][1] + Rd[2][2]*Rc[0][2];
    float m21 = Rd[2][0]*Rc[1][0] + Rd[2][1]*Rc[1][1] + Rd[2][2]*Rc[1][2];
    float m22 = Rd[2][0]*Rc[2][0] + Rd[2][1]*Rc[2][1] + Rd[2][2]*Rc[2][2];

    float t0 = 1.0f + m00 + m11 + m22;
    float t1 = 1.0f + m00 - m11 - m22;
    float t2 = 1.0f - m00 + m11 - m22;
    float t3 = 1.0f - m00 - m11 + m22;
    float qa0 = t0 > 0.0f ? sqrtf(t0) : 0.0f;
    float qa1 = t1 > 0.0f ? sqrtf(t1) : 0.0f;
    float qa2 = t2 > 0.0f ? sqrtf(t2) : 0.0f;
    float qa3 = t3 > 0.0f ? sqrtf(t3) : 0.0f;

    int best = 0; float qb = qa0;
    if (qa1 > qb) { best = 1; qb = qa1; }
    if (qa2 > qb) { best = 2; qb = qa2; }
    if (qa3 > qb) { best = 3; qb = qa3; }

    float q0, q1, q2, q3;
    if (best == 0)      { q0 = qa0*qa0; q1 = m21-m12; q2 = m02-m20; q3 = m10-m01; }
    else if (best == 1) { q0 = m21-m12; q1 = qa1*qa1; q2 = m10+m01; q3 = m02+m20; }
    else if (best == 2) { q0 = m02-m20; q1 = m10+m01; q2 = qa2*qa2; q3 = m12+m21; }
    else                { q0 = m10-m01; q1 = m20+m02; q2 = m21+m12; q3 = qa3*qa3; }
    float scale = area / (2.0f * fmaxf(qb, 0.1f));
    w0 = q0 * scale; w1 = q1 * scale; w2 = q2 * scale; w3 = q3 * scale;
}

__device__ __forceinline__ void face_math(const float* __restrict__ mesh,
                                          const float* __restrict__ cano,
                                          int i0, int i1, int i2,
                                          float& w0, float& w1, float& w2, float& w3) {
    face_core(loadv(cano, i0), loadv(cano, i1), loadv(cano, i2),
              loadv(mesh, i0), loadv(mesh, i1), loadv(mesh, i2),
              w0, w1, w2, w3);
}

__device__ __forceinline__ bool is_structured(int i0, int i1, int i2, int V) {
    int e1 = (i0 + 1 < V) ? i0 + 1 : i0 + 1 - V;
    int e2 = (i0 + 2 < V) ? i0 + 2 : i0 + 2 - V;
    return (i1 == e1) & (i2 == e2);
}

// ---------------- P1: counting sort -> residue bytes, block-major -----------
__global__ __launch_bounds__(1024)
void sort_kernel(const int* __restrict__ faces,
                 unsigned int* __restrict__ Hoff,      // [NBLK1][NB] off|cnt<<16
                 unsigned char* __restrict__ S1,       // [NBLK1][CHUNKF] residues
                 int* __restrict__ unstCnt,            // [NBLK1]
                 int* __restrict__ unstList,           // [NBLK1][CHUNKF] face idx
                 int F, int V, int NB, int CHUNKF) {
    __shared__ int h[NBMAX];
    __shared__ int off[NBMAX];
    __shared__ int cnt2[NBMAX];
    __shared__ int S0[CHMAX];
    __shared__ int wsum[16];
    __shared__ int unstC;

    int tid = threadIdx.x;
    for (int b = tid; b < NB; b += 1024) { h[b] = 0; cnt2[b] = 0; }
    if (tid == 0) unstC = 0;
    __syncthreads();

    int beg = blockIdx.x * CHUNKF;
    int end = min(F, beg + CHUNKF);

    // pass A: histogram + cache i0 in LDS; unstructured -> per-chunk list
    for (int f = beg + tid; f < end; f += 1024) {
        int i0 = faces[3 * f + 0];
        int i1 = faces[3 * f + 1];
        int i2 = faces[3 * f + 2];
        if (is_structured(i0, i1, i2, V)) {
            S0[f - beg] = i0;
            atomicAdd(&h[i0 >> 8], 1);
        } else {
            S0[f - beg] = -1;
            int p = atomicAdd(&unstC, 1);
            unstList[(size_t)blockIdx.x * CHUNKF + p] = f;
        }
    }
    __syncthreads();

    // exclusive prefix over h[0..NB) -> off[]
    {
        int e0 = (2 * tid < NB)     ? h[2 * tid]     : 0;
        int e1 = (2 * tid + 1 < NB) ? h[2 * tid + 1] : 0;
        int mysum = e0 + e1;
        int lane = tid & 63, wid = tid >> 6;
        int inc = mysum;
        #pragma unroll
        for (int d = 1; d < 64; d <<= 1) {
            int up = __shfl_up(inc, d);
            if (lane >= d) inc += up;
        }
        if (lane == 63) wsum[wid] = inc;
        __syncthreads();
        if (tid == 0) {
            int run = 0;
            #pragma unroll
            for (int i = 0; i < 16; ++i) { int x = wsum[i]; wsum[i] = run; run += x; }
        }
        __syncthreads();
        int excl = wsum[wid] + inc - mysum;
        if (2 * tid < NBMAX)     off[2 * tid]     = excl;
        if (2 * tid + 1 < NBMAX) off[2 * tid + 1] = excl + e0;
    }
    __syncthreads();

    // publish run descriptors (coalesced) + unstructured count
    for (int b = tid; b < NB; b += 1024)
        Hoff[(size_t)blockIdx.x * NB + b] = (unsigned int)off[b] | ((unsigned int)h[b] << 16);
    if (tid == 0) unstCnt[blockIdx.x] = unstC;

    // pass B: residue bytes into block-owned chunk (XCD-local scatter)
    unsigned char* S1blk = S1 + (size_t)blockIdx.x * CHUNKF;
    for (int j = tid; j < end - beg; j += 1024) {
        int i0 = S0[j];
        if (i0 >= 0) {
            int b = i0 >> 8;
            int p = atomicAdd(&cnt2[b], 1);
            S1blk[off[b] + p] = (unsigned char)(i0 & 0xFF);
        }
    }
}

// ---------------- P2: tiled transpose Hoff[NBLK1][NB] -> HoffT[NB][NBLK1] ---
__global__ __launch_bounds__(1024)
void transpose_kernel(const unsigned int* __restrict__ Hoff,
                      unsigned int* __restrict__ HoffT, int NB) {
    __shared__ unsigned int tile[64][65];
    int bx = blockIdx.x * 64;   // bucket base
    int by = blockIdx.y * 64;   // chunk base
    int tx = threadIdx.x;       // 0..63
    int ty = threadIdx.y;       // 0..15
    #pragma unroll
    for (int k = 0; k < 4; ++k) {
        int r = by + ty + k * 16;   // chunk
        int c = bx + tx;            // bucket
        tile[ty + k * 16][tx] = (c < NB) ? Hoff[(size_t)r * NB + c] : 0u;
    }
    __syncthreads();
    #pragma unroll
    for (int k = 0; k < 4; ++k) {
        int rowT = bx + ty + k * 16;    // bucket
        int colT = by + tx;             // chunk
        if (rowT < NB)
            HoffT[(size_t)rowT * NBLK1 + colT] = tile[tx][ty + k * 16];
    }
}

// ---------------- P3: per-bucket residue counting -> cntA[v] ----------------
__global__ __launch_bounds__(256)
void count_kernel(const unsigned int* __restrict__ HoffT,
                  const unsigned char* __restrict__ S1,
                  unsigned int* __restrict__ cntA,
                  int V, int NB, int CHUNKF) {
    int b = blockIdx.x;
    if (b >= NB) return;
    __shared__ unsigned int cnt_l[BS];
    cnt_l[threadIdx.x] = 0;
    __syncthreads();

    for (int r = threadIdx.x; r < NBLK1; r += 256) {
        unsigned int pc = HoffT[(size_t)b * NBLK1 + r];   // contiguous row
        int start = (int)(pc & 0xFFFFu);
        int cnt   = (int)(pc >> 16);
        const unsigned char* run = S1 + (size_t)r * CHUNKF + start;
        for (int j = 0; j < cnt; ++j)
            atomicAdd(&cnt_l[run[j]], 1u);
    }
    __syncthreads();
    int row = b * BS + (int)threadIdx.x;
    if (row < V) cntA[row] = cnt_l[threadIdx.x];
}

// ---------------- P4: fused math + window sum + normalize -------------------
__global__ __launch_bounds__(256)
void finish_kernel(const float* __restrict__ mesh,
                   const float* __restrict__ cano,
                   const unsigned int* __restrict__ cntA,
                   const int* __restrict__ unstCnt,
                   const int* __restrict__ unstList,
                   const int* __restrict__ faces,
                   float* __restrict__ out, int V, int CHUNKF) {
    __shared__ float4 Tw[BS + 2];
    __shared__ float Ew[BS][4];
    __shared__ int anyU;
    int base = blockIdx.x * BS;
    int t = threadIdx.x;

    if (t == 0) anyU = 0;
    __syncthreads();
    {   // OR-reduce the 512 per-chunk unstructured counts (2 KB, L2-broadcast)
        int u = unstCnt[t] | unstCnt[t + 256];
        if (u) atomicOr(&anyU, 1);
    }

    for (int j = t; j < BS + 2; j += 256) {
        int row = base - 2 + j;
        if (row < 0) row += V;
        if (row >= V) row -= V;
        unsigned int c = cntA[row];
        float4 res = make_float4(0.f, 0.f, 0.f, 0.f);
        if (c > 0) {
            int i1 = (row + 1 < V) ? row + 1 : row + 1 - V;
            int i2 = (row + 2 < V) ? row + 2 : row + 2 - V;
            float w0, w1, w2, w3;
            face_math(mesh, cano, row, i1, i2, w0, w1, w2, w3);
            float fc = (float)c;
            res = make_float4(w0 * fc, w1 * fc, w2 * fc, w3 * fc);
        }
        Tw[j] = res;
    }
    __syncthreads();   // Tw ready; anyU final

    if (anyU) {        // rare/never path: scan per-chunk lists, LDS fixup
        Ew[t][0] = Ew[t][1] = Ew[t][2] = Ew[t][3] = 0.f;
        __syncthreads();
        for (int blk = 0; blk < NBLK1; ++blk) {
            int cnt = unstCnt[blk];
            for (int j = t; j < cnt; j += 256) {
                int f = unstList[(size_t)blk * CHUNKF + j];
                int i0 = faces[3*f+0], i1 = faces[3*f+1], i2 = faces[3*f+2];
                float w0, w1, w2, w3;
                face_math(mesh, cano, i0, i1, i2, w0, w1, w2, w3);
                int tg[3] = {i0, i1, i2};
                #pragma unroll
                for (int k = 0; k < 3; ++k) {
                    int v = tg[k];
                    if (v >= base && v < base + BS && v < V) {
                        atomicAdd(&Ew[v - base][0], w0);
                        atomicAdd(&Ew[v - base][1], w1);
                        atomicAdd(&Ew[v - base][2], w2);
                        atomicAdd(&Ew[v - base][3], w3);
                    }
                }
            }
        }
        __syncthreads();
    }

    int v = base + t;
    if (v < V) {
        float4 a = Tw[t + 2], b4 = Tw[t + 1], c4 = Tw[t];
        float ex = 0.f, ey = 0.f, ez = 0.f, ew = 0.f;
        if (anyU) { ex = Ew[t][0]; ey = Ew[t][1]; ez = Ew[t][2]; ew = Ew[t][3]; }
        float x = a.x + b4.x + c4.x + ex;
        float y = a.y + b4.y + c4.y + ey;
        float z = a.z + b4.z + c4.z + ez;
        float w = a.w + b4.w + c4.w + ew;
        float n = sqrtf(x * x + y * y + z * z + w * w);
        float inv = 1.0f / fmaxf(n, 1e-6f);
        reinterpret_cast<float4*>(out)[v] = make_float4(x * inv, y * inv, z * inv, w * inv);
    }
}

// ================= fallback paths ===========================================
typedef _Float16 hf2 __attribute__((ext_vector_type(2)));

__device__ __forceinline__ void atomic_pk_add_f16(__half* base, float a, float b) {
#if __has_builtin(__builtin_amdgcn_global_atomic_fadd_v2f16)
    hf2 v; v.x = (_Float16)a; v.y = (_Float16)b;
    __builtin_amdgcn_global_atomic_fadd_v2f16(
        (__attribute__((address_space(1))) hf2*)base, v);
#else
    union { _Float16 h[2]; unsigned int u; } pk;
    pk.h[0] = (_Float16)a; pk.h[1] = (_Float16)b;
    asm volatile("global_atomic_pk_add_f16 %0, %1, off"
                 :: "v"(base), "v"(pk.u) : "memory");
#endif
}

__global__ void face_kernel_f16(const float* __restrict__ mesh,
                                const float* __restrict__ cano,
                                const int* __restrict__ faces,
                                __half* __restrict__ T, float* __restrict__ E,
                                int F, int V) {
    int f = blockIdx.x * blockDim.x + threadIdx.x;
    if (f >= F) return;
    int i0 = faces[3*f+0], i1 = faces[3*f+1], i2 = faces[3*f+2];
    float w0, w1, w2, w3;
    face_math(mesh, cano, i0, i1, i2, w0, w1, w2, w3);
    if (is_structured(i0, i1, i2, V)) {
        __half* t = T + 4 * (size_t)i0;
        atomic_pk_add_f16(t,     w0, w1);
        atomic_pk_add_f16(t + 2, w2, w3);
    } else {
        atomicAdd(&E[4*i0+0], w0); atomicAdd(&E[4*i0+1], w1);
        atomicAdd(&E[4*i0+2], w2); atomicAdd(&E[4*i0+3], w3);
        atomicAdd(&E[4*i1+0], w0); atomicAdd(&E[4*i1+1], w1);
        atomicAdd(&E[4*i1+2], w2); atomicAdd(&E[4*i1+3], w3);
        atomicAdd(&E[4*i2+0], w0); atomicAdd(&E[4*i2+1], w1);
        atomicAdd(&E[4*i2+2], w2); atomicAdd(&E[4*i2+3], w3);
    }
}

__global__ void finish_kernel_f16(const __half* __restrict__ T,
                                  const float* __restrict__ E,
                                  float* __restrict__ out, int V) {
    int v = blockIdx.x * blockDim.x + threadIdx.x;
    if (v >= V) return;
    int vm1 = (v >= 1) ? v - 1 : v - 1 + V;
    int vm2 = (v >= 2) ? v - 2 : v - 2 + V;
    const __half2* p0 = reinterpret_cast<const __half2*>(T + 4 * (size_t)v);
    const __half2* p1 = reinterpret_cast<const __half2*>(T + 4 * (size_t)vm1);
    const __half2* p2 = reinterpret_cast<const __half2*>(T + 4 * (size_t)vm2);
    float2 a01 = __half22float2(p0[0]), a23 = __half22float2(p0[1]);
    float2 b01 = __half22float2(p1[0]), b23 = __half22float2(p1[1]);
    float2 c01 = __half22float2(p2[0]), c23 = __half22float2(p2[1]);
    float4 e = reinterpret_cast<const float4*>(E)[v];
    float x = a01.x + b01.x + c01.x + e.x;
    float y = a01.y + b01.y + c01.y + e.y;
    float z = a23.x + b23.x + c23.x + e.z;
    float w = a23.y + b23.y + c23.y + e.w;
    float n = sqrtf(x * x + y * y + z * z + w * w);
    float inv = 1.0f / fmaxf(n, 1e-6f);
    reinterpret_cast<float4*>(out)[v] = make_float4(x * inv, y * inv, z * inv, w * inv);
}

__global__ void face_kernel_direct(const float* __restrict__ mesh,
                                   const float* __restrict__ cano,
                                   const int* __restrict__ faces,
                                   float* __restrict__ out, int F) {
    int f = blockIdx.x * blockDim.x + threadIdx.x;
    if (f >= F) return;
    int i0 = faces[3*f+0], i1 = faces[3*f+1], i2 = faces[3*f+2];
    float w0, w1, w2, w3;
    face_math(mesh, cano, i0, i1, i2, w0, w1, w2, w3);
    atomicAdd(&out[4*i0+0], w0); atomicAdd(&out[4*i0+1], w1);
    atomicAdd(&out[4*i0+2], w2); atomicAdd(&out[4*i0+3], w3);
    atomicAdd(&out[4*i1+0], w0); atomicAdd(&out[4*i1+1], w1);
    atomicAdd(&out[4*i1+2], w2); atomicAdd(&out[4*i1+3], w3);
    atomicAdd(&out[4*i2+0], w0); atomicAdd(&out[4*i2+1], w1);
    atomicAdd(&out[4*i2+2], w2); atomicAdd(&out[4*i2+3], w3);
}

__global__ void norm_kernel(float* __restrict__ out, int V) {
    int v = blockIdx.x * blockDim.x + threadIdx.x;
    if (v >= V) return;
    float4 q = reinterpret_cast<float4*>(out)[v];
    float n = sqrtf(q.x*q.x + q.y*q.y + q.z*q.z + q.w*q.w);
    float inv = 1.0f / fmaxf(n, 1e-6f);
    reinterpret_cast<float4*>(out)[v] = make_float4(q.x*inv, q.y*inv, q.z*inv, q.w*inv);
}

extern "C" void kernel_launch(void* const* d_in, const int* in_sizes, int n_in,
                              void* d_out, int out_size, void* d_ws, size_t ws_size,
                              hipStream_t stream) {
    const float* mesh  = (const float*)d_in[0];
    const float* cano  = (const float*)d_in[1];
    const int*   faces = (const int*)d_in[2];
    float* out = (float*)d_out;

    int V = in_sizes[0] / 3;
    int F = in_sizes[2] / 3;
    const int TB = 256;
    int NB = (V + BS - 1) / BS;
    int CHUNKF = (F + NBLK1 - 1) / NBLK1;

    // ws layout (byte offsets)
    size_t bHoff  = (size_t)NBLK1 * NBMAX * 4;                // 4 MB
    size_t bHoffT = (size_t)NBMAX * NBLK1 * 4;                // 4 MB
    size_t bS1    = (((size_t)NBLK1 * CHUNKF) + 15) & ~15ull; // ~1 MB
    size_t bCnt   = (size_t)V * 4;                            // 2 MB
    size_t bUC    = (size_t)NBLK1 * 4;                        // 2 KB
    size_t bUL    = (size_t)NBLK1 * CHUNKF * 4;               // 4 MB
    size_t needFull = bHoff + bHoffT + bS1 + bCnt + bUC + bUL;

    size_t bytesTf16 = (size_t)V * 4 * sizeof(__half);
    size_t bytesEf32 = (size_t)V * 4 * sizeof(float);

    if (ws_size >= needFull && NB <= NBMAX && CHUNKF <= CHMAX) {
        char* p = (char*)d_ws;
        unsigned int*  Hoff   = (unsigned int*)p;              p += bHoff;
        unsigned int*  HoffT  = (unsigned int*)p;              p += bHoffT;
        unsigned char* S1     = (unsigned char*)p;             p += bS1;
        unsigned int*  cntA   = (unsigned int*)p;              p += bCnt;
        int*           unstCnt = (int*)p;                      p += bUC;
        int*           unstList = (int*)p;

        sort_kernel<<<NBLK1, 1024, 0, stream>>>(faces, Hoff, S1, unstCnt, unstList,
                                                F, V, NB, CHUNKF);
        dim3 tgrid((NB + 63) / 64, NBLK1 / 64);
        transpose_kernel<<<tgrid, dim3(64, 16), 0, stream>>>(Hoff, HoffT, NB);
        count_kernel<<<NB, 256, 0, stream>>>(HoffT, S1, cntA, V, NB, CHUNKF);
        finish_kernel<<<NB, 256, 0, stream>>>(mesh, cano, cntA, unstCnt, unstList,
                                              faces, out, V, CHUNKF);
    } else if (ws_size >= bytesTf16 + bytesEf32) {
        __half* T = (__half*)d_ws;
        float*  E = (float*)((char*)d_ws + bytesTf16);
        (void)hipMemsetAsync(d_ws, 0, bytesTf16 + bytesEf32, stream);
        face_kernel_f16<<<(F + TB - 1) / TB, TB, 0, stream>>>(mesh, cano, faces, T, E, F, V);
        finish_kernel_f16<<<(V + TB - 1) / TB, TB, 0, stream>>>(T, E, out, V);
    } else {
        (void)hipMemsetAsync(out, 0, (size_t)V * 4 * sizeof(float), stream);
        face_kernel_direct<<<(F + TB - 1) / TB, TB, 0, stream>>>(mesh, cano, faces, out, F);
        norm_kernel<<<(V + TB - 1) / TB, TB, 0, stream>>>(out, V);
    }
}